// Round 14
// baseline (659.637 us; speedup 1.0000x reference)
//
#include <hip/hip_runtime.h>

#define NSEG 8192           // faces per set
#define NPTS (3 * NSEG)     // 24576 unified points [S | T | R]
#define NSUP 96             // 256-point super-tiles (32 per segment)
#define NXB  96             // one block per super-tile row (2 i-tiles/wave)
#define NYG  25             // y-groups: g<24 -> Y=2g,2g+1; g==24 -> Y=48

typedef short bf16x8 __attribute__((ext_vector_type(8)));   // 8 bf16 (4 VGPRs)
typedef float f32x16 __attribute__((ext_vector_type(16)));  // 16 fp32 acc
typedef unsigned short u16;

__device__ __forceinline__ u16 f2bf(float x) {              // RNE f32 -> bf16 bits
    unsigned u = __builtin_bit_cast(unsigned, x);
    return (u16)((u + 0x7FFFu + ((u >> 16) & 1u)) >> 16);
}
__device__ __forceinline__ float bf2f(u16 h) {
    unsigned u = ((unsigned)h) << 16;
    return __builtin_bit_cast(float, u);
}

__device__ __forceinline__ void compute_point(
    int seg, int f,
    const float* __restrict__ sv, const int* __restrict__ si,
    const float* __restrict__ tv, const int* __restrict__ ti,
    const float* __restrict__ rn, const float* __restrict__ rc,
    float& cx, float& cy, float& cz, float& nx, float& ny, float& nz)
{
    if (seg == 2) {
        nx = rn[3*f];   ny = rn[3*f+1]; nz = rn[3*f+2];
        cx = rc[3*f];   cy = rc[3*f+1]; cz = rc[3*f+2];
    } else {
        const float* v  = (seg == 0) ? sv : tv;
        const int*   nd = (seg == 0) ? si : ti;
        int i0 = nd[3*f], i1 = nd[3*f+1], i2 = nd[3*f+2];
        float ax = v[3*i0], ay = v[3*i0+1], az = v[3*i0+2];
        float bx = v[3*i1], by = v[3*i1+1], bz = v[3*i1+2];
        float gx = v[3*i2], gy = v[3*i2+1], gz = v[3*i2+2];
        float ux = ax-bx, uy = ay-by, uz = az-bz;
        float wx = gx-bx, wy = gy-by, wz = gz-bz;
        nx = 0.5f*(uy*wz - uz*wy);
        ny = 0.5f*(uz*wx - ux*wz);
        nz = 0.5f*(ux*wy - uy*wx);
        cx = (ax+bx+gx)*(1.0f/3.0f);
        cy = (ay+by+gy)*(1.0f/3.0f);
        cz = (az+bz+gz)*(1.0f/3.0f);
    }
}

// Feature rows (K=16 bf16), hi/lo split: t = A_t . B_t = 1+|ci-cj|^2 (~1e-3 abs err).
// Interleaved records: A-side point = {at[16], an[16]} (64 B), B-side = {bt[16], bn[16]}.
__global__ void setup_feats(const float* __restrict__ sv, const int* __restrict__ si,
                            const float* __restrict__ tv, const int* __restrict__ ti,
                            const float* __restrict__ rn, const float* __restrict__ rc,
                            u16* __restrict__ ws, float* __restrict__ out) {
    int p = blockIdx.x * 256 + threadIdx.x;
    if (p == 0) out[0] = 0.0f;          // d_out poisoned 0xAA before every launch
    if (p >= NPTS) return;
    int seg = p >> 13, f = p & (NSEG - 1);
    float cx, cy, cz, nx, ny, nz;
    compute_point(seg, f, sv, si, tv, ti, rn, rc, cx, cy, cz, nx, ny, nz);

    const u16 ONE = 0x3F80;
    float s = cx*cx + cy*cy + cz*cz;
    u16 chx = f2bf(cx), chy = f2bf(cy), chz = f2bf(cz);
    u16 clx = f2bf(cx - bf2f(chx)), cly = f2bf(cy - bf2f(chy)), clz = f2bf(cz - bf2f(chz));
    u16 sh  = f2bf(s);
    u16 sl  = f2bf(s - bf2f(sh));
    u16 m2hx = f2bf(-2.0f*bf2f(chx)), m2hy = f2bf(-2.0f*bf2f(chy)), m2hz = f2bf(-2.0f*bf2f(chz));
    u16 m2lx = f2bf(-2.0f*bf2f(clx)), m2ly = f2bf(-2.0f*bf2f(cly)), m2lz = f2bf(-2.0f*bf2f(clz));
    u16 nhx = f2bf(nx), nhy = f2bf(ny), nhz = f2bf(nz);
    u16 nlx = f2bf(nx - bf2f(nhx)), nly = f2bf(ny - bf2f(nhy)), nlz = f2bf(nz - bf2f(nhz));

    u16 at[16] = {chx,chy,chz, clx,cly,clz, chx,chy,chz, sh, sl, ONE, ONE, ONE, 0, 0};
    u16 bt[16] = {m2hx,m2hy,m2hz, m2hx,m2hy,m2hz, m2lx,m2ly,m2lz, ONE, ONE, sh, sl, ONE, 0, 0};
    u16 an[16] = {nhx,nhy,nhz, nlx,nly,nlz, nhx,nhy,nhz, 0,0,0,0,0,0,0};
    u16 bn[16] = {nhx,nhy,nhz, nhx,nhy,nhz, nlx,nly,nlz, 0,0,0,0,0,0,0};

    bf16x8* A8 = (bf16x8*)ws;            // A-record: frags [at0 at1 an0 an1] per point
    bf16x8* B8 = A8 + (size_t)NPTS*4;    // B-record: frags [bt0 bt1 bn0 bn1] per point
    bf16x8 v0, v1, v2, v3;
    #pragma unroll
    for (int k = 0; k < 8; ++k) { v0[k] = (short)at[k]; v1[k] = (short)at[k+8];
                                  v2[k] = (short)an[k]; v3[k] = (short)an[k+8]; }
    A8[(size_t)p*4+0] = v0; A8[(size_t)p*4+1] = v1; A8[(size_t)p*4+2] = v2; A8[(size_t)p*4+3] = v3;
    #pragma unroll
    for (int k = 0; k < 8; ++k) { v0[k] = (short)bt[k]; v1[k] = (short)bt[k+8];
                                  v2[k] = (short)bn[k]; v3[k] = (short)bn[k+8]; }
    B8[(size_t)p*4+0] = v0; B8[(size_t)p*4+1] = v1; B8[(size_t)p*4+2] = v2; B8[(size_t)p*4+3] = v3;
}

// Symmetric-pair kernel. R22 = R21 (LDS staging, tied-best 53.0 us) with:
//  (1) TRANSPOSED LDS layout [y][plane c][point p] (c = frag 0..3): each
//      32-lane half reads 512 consecutive bytes -> conflict-free (R21's
//      [p][c] layout put all lanes in banks {0,4,16,20}: 3.6M conflicts).
//      Halves alias 2-way (lane l vs l+32) which is free (m136).
//  (2) jt loop FULLY UNROLLED: every ds_read offset is a compile-time
//      immediate (16-bit field, max 12 KB used) -> zero per-iteration address
//      VALU, zero loop control. LDS reads are consumed near-issue, so no
//      long-lived-buffer spill hazard (R13's full-unroll spill was the
//      GLOBAL-load path hoisting buffers).
// Targets the ~120 unexplained busy-cycles/tile-pair of scaffolding on top of
// the 56-slot EPI. Gates: WRITE_SIZE ~75 B, FETCH ~7 MB, conflicts < 0.2M.
// Accumulation order within (X,y,jt,gq,i-tile) unchanged -> bitwise-same energy.
// Wrapped map over 256-pt super-tiles: (I,J) = (X, (X+Y)%96); mult = 2 except
// Y==0 (diagonal, once) and Y==48 (hit from both ends) -> 96+96+96*47*2 = 96^2. ✓
__launch_bounds__(256, 4)
__global__ void energy_mfma(const u16* __restrict__ ws, float* __restrict__ out) {
    const int tid  = threadIdx.x;
    const int lane = tid & 63, wid = tid >> 6;
    const int half = lane >> 5, r32 = lane & 31;

    const int X  = blockIdx.x;                // 0..95 (super-tile row)
    const int g  = blockIdx.y;                // 0..24
    const int y0  = (g < 24) ? 2*g : 48;
    const int ycnt = (g < 24) ? 2 : 1;
    const int gi = X >> 5;                    // 32 super-tiles per segment

    const bf16x8* A8 = (const bf16x8*)ws;
    const bf16x8* B8 = A8 + (size_t)NPTS*4;

    // two persistent 32-row i-tiles per wave: rows pi and pi+128
    const int pi = X*256 + wid*32 + r32;
    const bf16x8 at0 = A8[pi*4 + half];
    const bf16x8 an0 = A8[pi*4 + 2 + half];
    const bf16x8 at1 = A8[pi*4 + 512 + half];        // +128 points * 4 frags
    const bf16x8 an1 = A8[pi*4 + 514 + half];

    // stage B-supertiles into LDS, TRANSPOSED: [y][plane c][point p]
    __shared__ bf16x8 ldsB[2][4][256];               // 32 KB
    #pragma unroll
    for (int k = 0; k < 2; ++k) {
        if (k < ycnt) {
            int J = X + y0 + k; if (J >= NSUP) J -= NSUP;
            const bf16x8* srcB = B8 + J*1024;
            #pragma unroll
            for (int rep = 0; rep < 4; ++rep) {      // coalesced 16 B/lane reads
                int f = rep*256 + tid;               // linear frag index
                ldsB[k][f & 3][f >> 2] = srcB[f];    // c = f&3, p = f>>2
            }
        }
    }
    __syncthreads();

    f32x16 Z;
    #pragma unroll
    for (int k = 0; k < 16; ++k) Z[k] = 0.0f;

    // batched rcp: one v_rcp per 4 pairs; two independent partial chains
#define EPI(CT, CN, TS0, TS1) do {                                            \
        _Pragma("unroll")                                                     \
        for (int gq = 0; gq < 4; ++gq) {                                      \
            float t0 = CT[4*gq+0], t1 = CT[4*gq+1];                           \
            float t2 = CT[4*gq+2], t3 = CT[4*gq+3];                           \
            float q0 = t0*t0, q1 = t1*t1, q2 = t2*t2, q3 = t3*t3;             \
            float s01 = q0*q1, s23 = q2*q3;                                   \
            float r   = __builtin_amdgcn_rcpf(s01*s23);                       \
            float u   = __builtin_fmaf(CN[4*gq+1], q0, CN[4*gq+0]*q1);        \
            float v   = __builtin_fmaf(CN[4*gq+3], q2, CN[4*gq+2]*q3);        \
            float num = __builtin_fmaf(v, s01, u*s23);                        \
            if (gq & 1) TS1 = __builtin_fmaf(num, r, TS1);                    \
            else        TS0 = __builtin_fmaf(num, r, TS0);                    \
        }                                                                     \
    } while (0)

    float acc = 0.0f;
    #pragma unroll 1
    for (int yy = 0; yy < ycnt; ++yy) {
        const int y = y0 + yy;
        int J = X + y; if (J >= NSUP) J -= NSUP;
        const int jg = J >> 5;
        float base_w;
        if (gi == jg)                 base_w = (gi == 2) ? 2.0f : 1.8f;
        else if (gi == 2 || jg == 2)  base_w = -1.0f;
        else                          base_w = -0.8f;
        const float w = base_w * ((y == 0 || y == 48) ? 1.0f : 2.0f);

        // per-lane LDS base pointers (plane half / 2+half, point r32);
        // jt advances by +32 points = +512 B -> compile-time imm offsets
        const bf16x8* Bt = &ldsB[yy][half][r32];
        const bf16x8* Bn = &ldsB[yy][2 + half][r32];

        float tsA0 = 0.0f, tsA1 = 0.0f;       // i-tile 0 partials
        float tsB0 = 0.0f, tsB1 = 0.0f;       // i-tile 1 partials
        #pragma unroll
        for (int jt = 0; jt < 8; ++jt) {
            bf16x8 bt = Bt[jt*32];            // ds_read_b128, base + imm offset
            bf16x8 bn = Bn[jt*32];            // conflict-free (consecutive pts)

            f32x16 ct, cn;
            ct = __builtin_amdgcn_mfma_f32_32x32x16_bf16(at0, bt, Z, 0, 0, 0);
            cn = __builtin_amdgcn_mfma_f32_32x32x16_bf16(an0, bn, Z, 0, 0, 0);
            EPI(ct, cn, tsA0, tsA1);
            ct = __builtin_amdgcn_mfma_f32_32x32x16_bf16(at1, bt, Z, 0, 0, 0);
            cn = __builtin_amdgcn_mfma_f32_32x32x16_bf16(an1, bn, Z, 0, 0, 0);
            EPI(ct, cn, tsB0, tsB1);
        }
        acc = __builtin_fmaf(w, tsA0 + tsA1, acc);
        acc = __builtin_fmaf(w, tsB0 + tsB1, acc);
    }
#undef EPI

    // wave shuffle reduce -> 4 partials -> one atomic per block
    for (int off = 32; off; off >>= 1) acc += __shfl_down(acc, off, 64);
    __shared__ float partial[4];
    if ((tid & 63) == 0) partial[wid] = acc;
    __syncthreads();
    if (tid == 0)
        atomicAdd(out, (partial[0] + partial[1]) + (partial[2] + partial[3]));
}

extern "C" void kernel_launch(void* const* d_in, const int* in_sizes, int n_in,
                              void* d_out, int out_size, void* d_ws, size_t ws_size,
                              hipStream_t stream) {
    const float* sv = (const float*)d_in[0];
    const int*   si = (const int*)d_in[1];
    const float* tv = (const float*)d_in[2];
    const int*   ti = (const int*)d_in[3];
    const float* rn = (const float*)d_in[4];
    const float* rc = (const float*)d_in[5];
    float* out = (float*)d_out;
    u16*   ws  = (u16*)d_ws;                      // 2 x 24576 x 64 B = 3 MB features

    setup_feats<<<NPTS/256, 256, 0, stream>>>(sv, si, tv, ti, rn, rc, ws, out);
    dim3 grid(NXB, NYG);                          // 96 x 25 = 2400 blocks of 256
    energy_mfma<<<grid, 256, 0, stream>>>(ws, out);
}

// Round 15
// 111.048 us; speedup vs baseline: 5.9401x; 5.9401x over previous
//
#include <hip/hip_runtime.h>

#define NSEG 8192           // faces per set
#define NPTS (3 * NSEG)     // 24576 unified points [S | T | R]
#define NSUP 96             // 256-point super-tiles (32 per segment)
#define NXB  96             // one block per super-tile row (2 i-tiles/wave)
#define NYG  25             // y-groups: g<24 -> Y=2g,2g+1; g==24 -> Y=48

typedef short bf16x8 __attribute__((ext_vector_type(8)));   // 8 bf16 (4 VGPRs)
typedef float f32x16 __attribute__((ext_vector_type(16)));  // 16 fp32 acc
typedef unsigned short u16;

__device__ __forceinline__ u16 f2bf(float x) {              // RNE f32 -> bf16 bits
    unsigned u = __builtin_bit_cast(unsigned, x);
    return (u16)((u + 0x7FFFu + ((u >> 16) & 1u)) >> 16);
}
__device__ __forceinline__ float bf2f(u16 h) {
    unsigned u = ((unsigned)h) << 16;
    return __builtin_bit_cast(float, u);
}

__device__ __forceinline__ void compute_point(
    int seg, int f,
    const float* __restrict__ sv, const int* __restrict__ si,
    const float* __restrict__ tv, const int* __restrict__ ti,
    const float* __restrict__ rn, const float* __restrict__ rc,
    float& cx, float& cy, float& cz, float& nx, float& ny, float& nz)
{
    if (seg == 2) {
        nx = rn[3*f];   ny = rn[3*f+1]; nz = rn[3*f+2];
        cx = rc[3*f];   cy = rc[3*f+1]; cz = rc[3*f+2];
    } else {
        const float* v  = (seg == 0) ? sv : tv;
        const int*   nd = (seg == 0) ? si : ti;
        int i0 = nd[3*f], i1 = nd[3*f+1], i2 = nd[3*f+2];
        float ax = v[3*i0], ay = v[3*i0+1], az = v[3*i0+2];
        float bx = v[3*i1], by = v[3*i1+1], bz = v[3*i1+2];
        float gx = v[3*i2], gy = v[3*i2+1], gz = v[3*i2+2];
        float ux = ax-bx, uy = ay-by, uz = az-bz;
        float wx = gx-bx, wy = gy-by, wz = gz-bz;
        nx = 0.5f*(uy*wz - uz*wy);
        ny = 0.5f*(uz*wx - ux*wz);
        nz = 0.5f*(ux*wy - uy*wx);
        cx = (ax+bx+gx)*(1.0f/3.0f);
        cy = (ay+by+gy)*(1.0f/3.0f);
        cz = (az+bz+gz)*(1.0f/3.0f);
    }
}

// Feature rows (K=16 bf16), hi/lo split: t = A_t . B_t = 1+|ci-cj|^2 (~1e-3 abs err).
// Interleaved records: A-side point = {at[16], an[16]} (64 B), B-side = {bt[16], bn[16]}.
__global__ void setup_feats(const float* __restrict__ sv, const int* __restrict__ si,
                            const float* __restrict__ tv, const int* __restrict__ ti,
                            const float* __restrict__ rn, const float* __restrict__ rc,
                            u16* __restrict__ ws, float* __restrict__ out) {
    int p = blockIdx.x * 256 + threadIdx.x;
    if (p == 0) out[0] = 0.0f;          // d_out poisoned 0xAA before every launch
    if (p >= NPTS) return;
    int seg = p >> 13, f = p & (NSEG - 1);
    float cx, cy, cz, nx, ny, nz;
    compute_point(seg, f, sv, si, tv, ti, rn, rc, cx, cy, cz, nx, ny, nz);

    const u16 ONE = 0x3F80;
    float s = cx*cx + cy*cy + cz*cz;
    u16 chx = f2bf(cx), chy = f2bf(cy), chz = f2bf(cz);
    u16 clx = f2bf(cx - bf2f(chx)), cly = f2bf(cy - bf2f(chy)), clz = f2bf(cz - bf2f(chz));
    u16 sh  = f2bf(s);
    u16 sl  = f2bf(s - bf2f(sh));
    u16 m2hx = f2bf(-2.0f*bf2f(chx)), m2hy = f2bf(-2.0f*bf2f(chy)), m2hz = f2bf(-2.0f*bf2f(chz));
    u16 m2lx = f2bf(-2.0f*bf2f(clx)), m2ly = f2bf(-2.0f*bf2f(cly)), m2lz = f2bf(-2.0f*bf2f(clz));
    u16 nhx = f2bf(nx), nhy = f2bf(ny), nhz = f2bf(nz);
    u16 nlx = f2bf(nx - bf2f(nhx)), nly = f2bf(ny - bf2f(nhy)), nlz = f2bf(nz - bf2f(nhz));

    u16 at[16] = {chx,chy,chz, clx,cly,clz, chx,chy,chz, sh, sl, ONE, ONE, ONE, 0, 0};
    u16 bt[16] = {m2hx,m2hy,m2hz, m2hx,m2hy,m2hz, m2lx,m2ly,m2lz, ONE, ONE, sh, sl, ONE, 0, 0};
    u16 an[16] = {nhx,nhy,nhz, nlx,nly,nlz, nhx,nhy,nhz, 0,0,0,0,0,0,0};
    u16 bn[16] = {nhx,nhy,nhz, nhx,nhy,nhz, nlx,nly,nlz, 0,0,0,0,0,0,0};

    bf16x8* A8 = (bf16x8*)ws;            // A-record: frags [at0 at1 an0 an1] per point
    bf16x8* B8 = A8 + (size_t)NPTS*4;    // B-record: frags [bt0 bt1 bn0 bn1] per point
    bf16x8 v0, v1, v2, v3;
    #pragma unroll
    for (int k = 0; k < 8; ++k) { v0[k] = (short)at[k]; v1[k] = (short)at[k+8];
                                  v2[k] = (short)an[k]; v3[k] = (short)an[k+8]; }
    A8[(size_t)p*4+0] = v0; A8[(size_t)p*4+1] = v1; A8[(size_t)p*4+2] = v2; A8[(size_t)p*4+3] = v3;
    #pragma unroll
    for (int k = 0; k < 8; ++k) { v0[k] = (short)bt[k]; v1[k] = (short)bt[k+8];
                                  v2[k] = (short)bn[k]; v3[k] = (short)bn[k+8]; }
    B8[(size_t)p*4+0] = v0; B8[(size_t)p*4+1] = v1; B8[(size_t)p*4+2] = v2; B8[(size_t)p*4+3] = v3;
}

// Symmetric-pair kernel. R23 = R21 byte-for-byte (tied-best 53.0 us, LDS
// staging, #pragma unroll 2 — the ONLY stable schedule; R22's full unroll
// hoisted 16 ds_reads -> 32 live buffers -> 1.3 GB scratch, 612 us, 4th
// confirmation of the live-range spill law) with ONLY the layout fix:
// LDS stored TRANSPOSED [y][plane c][point p] so the jt read Bt[jt*32+r32]
// has each 32-lane half reading 512 consecutive bytes -> conflict-free
// (R21's [p][c] put all lanes in banks {0,4,16,20} = 3.6M conflict cycles;
// lane l / l+32 2-way alias is free per m136). Staging write scatters but is
// a one-time pass. This is the last clean lever; if dur stays ~53 us the
// kernel is at its structural floor (VALU-busy 34 us invariant over 9
// variants; 3 load paths identical; all occupancy/pipeline levers null/spill).
// Accumulation order within (X,y,jt,gq,i-tile) unchanged -> bitwise-same energy.
// Wrapped map over 256-pt super-tiles: (I,J) = (X, (X+Y)%96); mult = 2 except
// Y==0 (diagonal, once) and Y==48 (hit from both ends) -> 96+96+96*47*2 = 96^2. ✓
__launch_bounds__(256, 4)
__global__ void energy_mfma(const u16* __restrict__ ws, float* __restrict__ out) {
    const int tid  = threadIdx.x;
    const int lane = tid & 63, wid = tid >> 6;
    const int half = lane >> 5, r32 = lane & 31;

    const int X  = blockIdx.x;                // 0..95 (super-tile row)
    const int g  = blockIdx.y;                // 0..24
    const int y0  = (g < 24) ? 2*g : 48;
    const int ycnt = (g < 24) ? 2 : 1;
    const int gi = X >> 5;                    // 32 super-tiles per segment

    const bf16x8* A8 = (const bf16x8*)ws;
    const bf16x8* B8 = A8 + (size_t)NPTS*4;

    // two persistent 32-row i-tiles per wave: rows pi and pi+128
    const int pi = X*256 + wid*32 + r32;
    const bf16x8 at0 = A8[pi*4 + half];
    const bf16x8 an0 = A8[pi*4 + 2 + half];
    const bf16x8 at1 = A8[pi*4 + 512 + half];        // +128 points * 4 frags
    const bf16x8 an1 = A8[pi*4 + 514 + half];

    // stage B-supertiles into LDS, TRANSPOSED: [y][plane c][point p]
    __shared__ bf16x8 ldsB[2][4][256];               // 32 KB
    #pragma unroll
    for (int k = 0; k < 2; ++k) {
        if (k < ycnt) {
            int J = X + y0 + k; if (J >= NSUP) J -= NSUP;
            const bf16x8* srcB = B8 + J*1024;
            #pragma unroll
            for (int rep = 0; rep < 4; ++rep) {      // coalesced 16 B/lane reads
                int f = rep*256 + tid;               // linear frag index
                ldsB[k][f & 3][f >> 2] = srcB[f];    // c = f&3, p = f>>2
            }
        }
    }
    __syncthreads();

    f32x16 Z;
    #pragma unroll
    for (int k = 0; k < 16; ++k) Z[k] = 0.0f;

    // batched rcp: one v_rcp per 4 pairs; two independent partial chains
#define EPI(CT, CN, TS0, TS1) do {                                            \
        _Pragma("unroll")                                                     \
        for (int gq = 0; gq < 4; ++gq) {                                      \
            float t0 = CT[4*gq+0], t1 = CT[4*gq+1];                           \
            float t2 = CT[4*gq+2], t3 = CT[4*gq+3];                           \
            float q0 = t0*t0, q1 = t1*t1, q2 = t2*t2, q3 = t3*t3;             \
            float s01 = q0*q1, s23 = q2*q3;                                   \
            float r   = __builtin_amdgcn_rcpf(s01*s23);                       \
            float u   = __builtin_fmaf(CN[4*gq+1], q0, CN[4*gq+0]*q1);        \
            float v   = __builtin_fmaf(CN[4*gq+3], q2, CN[4*gq+2]*q3);        \
            float num = __builtin_fmaf(v, s01, u*s23);                        \
            if (gq & 1) TS1 = __builtin_fmaf(num, r, TS1);                    \
            else        TS0 = __builtin_fmaf(num, r, TS0);                    \
        }                                                                     \
    } while (0)

    float acc = 0.0f;
    #pragma unroll 1
    for (int yy = 0; yy < ycnt; ++yy) {
        const int y = y0 + yy;
        int J = X + y; if (J >= NSUP) J -= NSUP;
        const int jg = J >> 5;
        float base_w;
        if (gi == jg)                 base_w = (gi == 2) ? 2.0f : 1.8f;
        else if (gi == 2 || jg == 2)  base_w = -1.0f;
        else                          base_w = -0.8f;
        const float w = base_w * ((y == 0 || y == 48) ? 1.0f : 2.0f);

        // per-lane LDS base pointers (plane half / 2+half, point r32);
        // each 32-lane half reads 512 consecutive bytes -> conflict-free
        const bf16x8* Bt = &ldsB[yy][half][r32];
        const bf16x8* Bn = &ldsB[yy][2 + half][r32];

        float tsA0 = 0.0f, tsA1 = 0.0f;       // i-tile 0 partials
        float tsB0 = 0.0f, tsB1 = 0.0f;       // i-tile 1 partials
        #pragma unroll 2
        for (int jt = 0; jt < 8; ++jt) {
            bf16x8 bt = Bt[jt*32];            // ds_read_b128, +512 B per jt
            bf16x8 bn = Bn[jt*32];

            f32x16 ct, cn;
            ct = __builtin_amdgcn_mfma_f32_32x32x16_bf16(at0, bt, Z, 0, 0, 0);
            cn = __builtin_amdgcn_mfma_f32_32x32x16_bf16(an0, bn, Z, 0, 0, 0);
            EPI(ct, cn, tsA0, tsA1);
            ct = __builtin_amdgcn_mfma_f32_32x32x16_bf16(at1, bt, Z, 0, 0, 0);
            cn = __builtin_amdgcn_mfma_f32_32x32x16_bf16(an1, bn, Z, 0, 0, 0);
            EPI(ct, cn, tsB0, tsB1);
        }
        acc = __builtin_fmaf(w, tsA0 + tsA1, acc);
        acc = __builtin_fmaf(w, tsB0 + tsB1, acc);
    }
#undef EPI

    // wave shuffle reduce -> 4 partials -> one atomic per block
    for (int off = 32; off; off >>= 1) acc += __shfl_down(acc, off, 64);
    __shared__ float partial[4];
    if ((tid & 63) == 0) partial[wid] = acc;
    __syncthreads();
    if (tid == 0)
        atomicAdd(out, (partial[0] + partial[1]) + (partial[2] + partial[3]));
}

extern "C" void kernel_launch(void* const* d_in, const int* in_sizes, int n_in,
                              void* d_out, int out_size, void* d_ws, size_t ws_size,
                              hipStream_t stream) {
    const float* sv = (const float*)d_in[0];
    const int*   si = (const int*)d_in[1];
    const float* tv = (const float*)d_in[2];
    const int*   ti = (const int*)d_in[3];
    const float* rn = (const float*)d_in[4];
    const float* rc = (const float*)d_in[5];
    float* out = (float*)d_out;
    u16*   ws  = (u16*)d_ws;                      // 2 x 24576 x 64 B = 3 MB features

    setup_feats<<<NPTS/256, 256, 0, stream>>>(sv, si, tv, ti, rn, rc, ws, out);
    dim3 grid(NXB, NYG);                          // 96 x 25 = 2400 blocks of 256
    energy_mfma<<<grid, 256, 0, stream>>>(ws, out);
}